// Round 22
// baseline (743.294 us; speedup 1.0000x reference)
//
#include <hip/hip_runtime.h>
#include <hip/hip_bf16.h>
#include <cstddef>

#define N_NODES 131072
#define N_EDGES 1048576
#define NF 78
#define NB 512
#define BNR 0.9999950000374996f  // 1/sqrt(1+1e-5)

typedef float v2f __attribute__((ext_vector_type(2)));

__device__ __forceinline__ float wave_red_sum(float v) {
  for (int off = 32; off > 0; off >>= 1) v += __shfl_down(v, off);
  return v;
}

__device__ __forceinline__ float bf2f(unsigned short u) {
  return __uint_as_float(((unsigned)u) << 16);
}

__device__ __forceinline__ unsigned f2bf_rn(float x) {  // round-to-nearest-even bf16 bits
  unsigned u = __float_as_uint(x);
  return (u + 0x7fffu + ((u >> 16) & 1u)) >> 16;
}

__device__ __forceinline__ unsigned char f2fp8(float x) {  // OCP e4m3 via HW cvt
  int p = __builtin_amdgcn_cvt_pk_fp8_f32(x, x, 0, false);
  return (unsigned char)(p & 0xff);
}

// ---------------- graph setup ----------------
__global__ void k_count(const int* __restrict__ dst, int* __restrict__ cnt) {
  int e = blockIdx.x * 256 + threadIdx.x;
  if (e < N_EDGES) atomicAdd(&cnt[dst[e]], 1);
}

__global__ void k_dis(const int* __restrict__ cnt, float* __restrict__ dis) {
  int n = blockIdx.x * 256 + threadIdx.x;
  if (n < N_NODES) dis[n] = rsqrtf(1.0f + (float)cnt[n]);
}

__global__ void k_scan1(const int* __restrict__ cnt, int* __restrict__ offs, int* __restrict__ bsum) {
  __shared__ int s[512];
  int gid = blockIdx.x * 512 + threadIdx.x;
  int v = cnt[gid];
  s[threadIdx.x] = v; __syncthreads();
  for (int off = 1; off < 512; off <<= 1) {
    int t = (threadIdx.x >= off) ? s[threadIdx.x - off] : 0;
    __syncthreads();
    s[threadIdx.x] += t;
    __syncthreads();
  }
  offs[gid] = s[threadIdx.x] - v;               // exclusive
  if (threadIdx.x == 511) bsum[blockIdx.x] = s[511];
}

__global__ void k_scan2(int* __restrict__ bsum) {  // 1 block, 256 threads
  __shared__ int s[256];
  int v = bsum[threadIdx.x];
  s[threadIdx.x] = v; __syncthreads();
  for (int off = 1; off < 256; off <<= 1) {
    int t = (threadIdx.x >= off) ? s[threadIdx.x - off] : 0;
    __syncthreads();
    s[threadIdx.x] += t;
    __syncthreads();
  }
  bsum[threadIdx.x] = s[threadIdx.x] - v;       // exclusive
}

__global__ void k_scan3(int* __restrict__ offs, const int* __restrict__ bsum) {
  int gid = blockIdx.x * 512 + threadIdx.x;
  offs[gid] += bsum[blockIdx.x];
}

__global__ void k_fill(const int* __restrict__ src, const int* __restrict__ dst,
                       const int* __restrict__ offs, int* __restrict__ cursor,
                       const float* __restrict__ dis, int* __restrict__ csr,
                       float* __restrict__ cf) {
  int e = blockIdx.x * 256 + threadIdx.x;
  if (e < N_EDGES) {
    int s = src[e], d = dst[e];
    int pos = offs[d] + atomicAdd(&cursor[d], 1);
    csr[pos] = s;
    cf[pos] = dis[s] * dis[d];
  }
}

// ---------------- GCN layer ----------------
// t = h @ W  (layer 1, f32 input, no gate), output fp8 e4m3, row stride 128B
__global__ __launch_bounds__(256) void k_gemm_f32(const float* __restrict__ h,
                                                  const float* __restrict__ W,
                                                  unsigned char* __restrict__ t8) {
  __shared__ float hs[64 * NF];
  __shared__ float Ws[NF * NF];
  int n0 = blockIdx.x * 64;
  int tid = threadIdx.x;
  for (int i = tid; i < NF * NF; i += 256) Ws[i] = W[i];
  for (int i = tid; i < 64 * NF; i += 256) hs[i] = h[(size_t)n0 * NF + i];
  __syncthreads();
  int rg = tid >> 4, cg = tid & 15;
  int r0 = rg * 4, c0 = cg * 5;
  float acc[4][5] = {};
  for (int k = 0; k < NF; ++k) {
    float wv[5];
#pragma unroll
    for (int j = 0; j < 5; ++j) wv[j] = (c0 + j < NF) ? Ws[k * NF + c0 + j] : 0.f;
#pragma unroll
    for (int i = 0; i < 4; ++i) {
      float hv = hs[(r0 + i) * NF + k];
#pragma unroll
      for (int j = 0; j < 5; ++j) acc[i][j] += hv * wv[j];
    }
  }
  for (int i = 0; i < 4; ++i)
    for (int j = 0; j < 5; ++j) {
      int c = c0 + j;
      if (c < NF) t8[(size_t)(n0 + r0 + i) * 128 + c] = f2fp8(acc[i][j]);
    }
}

// t = (h .* gate) @ W  (layers 2,3; h bf16), output fp8
__global__ __launch_bounds__(256) void k_gemm_bf16(const unsigned short* __restrict__ h,
                                                   const float* __restrict__ gate,
                                                   const float* __restrict__ W,
                                                   unsigned char* __restrict__ t8) {
  __shared__ float hs[64 * NF];
  __shared__ float Ws[NF * NF];
  int n0 = blockIdx.x * 64;
  int tid = threadIdx.x;
  for (int i = tid; i < NF * NF; i += 256) Ws[i] = W[i];
  for (int i = tid; i < 64 * NF; i += 256) {
    int r = i / NF;
    hs[i] = bf2f(h[(size_t)n0 * NF + i]) * gate[n0 + r];
  }
  __syncthreads();
  int rg = tid >> 4, cg = tid & 15;
  int r0 = rg * 4, c0 = cg * 5;
  float acc[4][5] = {};
  for (int k = 0; k < NF; ++k) {
    float wv[5];
#pragma unroll
    for (int j = 0; j < 5; ++j) wv[j] = (c0 + j < NF) ? Ws[k * NF + c0 + j] : 0.f;
#pragma unroll
    for (int i = 0; i < 4; ++i) {
      float hv = hs[(r0 + i) * NF + k];
#pragma unroll
      for (int j = 0; j < 5; ++j) acc[i][j] += hv * wv[j];
    }
  }
  for (int i = 0; i < 4; ++i)
    for (int j = 0; j < 5; ++j) {
      int c = c0 + j;
      if (c < NF) t8[(size_t)(n0 + r0 + i) * 128 + c] = f2fp8(acc[i][j]);
    }
}

// out = relu(bn(agg + t*selfc + b)); also spre = out . Wp  (one wave per node)
// 3-slot gather: lanes split into 3 groups of 20; each group handles one edge/iter.
__global__ __launch_bounds__(256) void k_agg(const unsigned* __restrict__ t32, const int* __restrict__ offs,
                                             const int* __restrict__ cnt, const int* __restrict__ csr,
                                             const float* __restrict__ cf, const float* __restrict__ dis,
                                             const float* __restrict__ bias, const float* __restrict__ bn,
                                             const float* __restrict__ Wp,
                                             unsigned* __restrict__ hout, float* __restrict__ spre) {
  __shared__ int   sIdxL[4 * 68];
  __shared__ float sCoefL[4 * 68];
  int wave = threadIdx.x >> 6, lane = threadIdx.x & 63;
  int n = blockIdx.x * 4 + wave;
  float disn = dis[n];
  int st = offs[n], cn = cnt[n];
  int cn1 = cn < 64 ? cn : 64;
  int base = wave * 68;
  if (lane < cn1) {
    int s = csr[st + lane];
    sIdxL[base + lane] = s * 32;          // uint stride 32 (128B rows)
    sCoefL[base + lane] = cf[st + lane];
  }
  if (lane < 3) {                          // pad 3 entries past cn1
    sIdxL[base + cn1 + lane] = 0;
    sCoefL[base + cn1 + lane] = 0.f;
  }
  int slot = lane / 20;                    // 0,1,2 active; 3 = lanes 60-63 (zero coef)
  int li = lane - slot * 20;               // 0..19
  float selfc = disn * disn;
  float a0 = 0.f, a1 = 0.f, a2 = 0.f, a3 = 0.f;
  if (slot == 0) {
    unsigned u = t32[(size_t)n * 32 + li];
    v2f f01 = __builtin_amdgcn_cvt_pk_f32_fp8((int)u, false);
    v2f f23 = __builtin_amdgcn_cvt_pk_f32_fp8((int)u, true);
    a0 = f01[0] * selfc; a1 = f01[1] * selfc;
    a2 = f23[0] * selfc; a3 = f23[1] * selfc;
  }
#pragma unroll 2
  for (int j = 0; j < cn1; j += 3) {
    int idx = sIdxL[base + j + slot];      // slot 3 reads pad (discarded, coef 0)
    float c = (slot < 3) ? sCoefL[base + j + slot] : 0.f;
    unsigned u = t32[idx + li];
    v2f f01 = __builtin_amdgcn_cvt_pk_f32_fp8((int)u, false);
    v2f f23 = __builtin_amdgcn_cvt_pk_f32_fp8((int)u, true);
    a0 += c * f01[0]; a1 += c * f01[1];
    a2 += c * f23[0]; a3 += c * f23[1];
  }
  for (int j = 64; j < cn; ++j) {          // safety tail (slot 0 lanes only)
    if (slot == 0) {
      int sb = csr[st + j] * 32; float c = cf[st + j];
      unsigned u = t32[sb + li];
      v2f f01 = __builtin_amdgcn_cvt_pk_f32_fp8((int)u, false);
      v2f f23 = __builtin_amdgcn_cvt_pk_f32_fp8((int)u, true);
      a0 += c * f01[0]; a1 += c * f01[1];
      a2 += c * f23[0]; a3 += c * f23[1];
    }
  }
  // merge slots: lanes 0-19 accumulate from lanes +20 and +40
  a0 += __shfl(a0, lane + 20) + __shfl(a0, lane + 40);
  a1 += __shfl(a1, lane + 20) + __shfl(a1, lane + 40);
  a2 += __shfl(a2, lane + 20) + __shfl(a2, lane + 40);
  a3 += __shfl(a3, lane + 20) + __shfl(a3, lane + 40);
  float p = 0.f;
  if (lane < 20) {
    int f0 = 4 * lane;
    float h0v, h1v, h2v, h3v;
    if (lane < 19) {
      float4 bi = *reinterpret_cast<const float4*>(bias + f0);
      float4 gm = *reinterpret_cast<const float4*>(bn + f0);
      float2 btA = *reinterpret_cast<const float2*>(bn + NF + f0);
      float2 btB = *reinterpret_cast<const float2*>(bn + NF + f0 + 2);
      float4 wp = *reinterpret_cast<const float4*>(Wp + f0);
      h0v = fmaxf(0.f, gm.x * BNR * (a0 + bi.x) + btA.x);
      h1v = fmaxf(0.f, gm.y * BNR * (a1 + bi.y) + btA.y);
      h2v = fmaxf(0.f, gm.z * BNR * (a2 + bi.z) + btB.x);
      h3v = fmaxf(0.f, gm.w * BNR * (a3 + bi.w) + btB.y);
      hout[(size_t)n * 39 + 2 * lane]     = f2bf_rn(h0v) | (f2bf_rn(h1v) << 16);
      hout[(size_t)n * 39 + 2 * lane + 1] = f2bf_rn(h2v) | (f2bf_rn(h3v) << 16);
      p = h0v * wp.x + h1v * wp.y + h2v * wp.z + h3v * wp.w;
    } else {  // features 76,77 only
      float2 bi = *reinterpret_cast<const float2*>(bias + 76);
      float2 gm = *reinterpret_cast<const float2*>(bn + 76);
      float2 bt = *reinterpret_cast<const float2*>(bn + NF + 76);
      float2 wp = *reinterpret_cast<const float2*>(Wp + 76);
      h0v = fmaxf(0.f, gm.x * BNR * (a0 + bi.x) + bt.x);
      h1v = fmaxf(0.f, gm.y * BNR * (a1 + bi.y) + bt.y);
      hout[(size_t)n * 39 + 38] = f2bf_rn(h0v) | (f2bf_rn(h1v) << 16);
      p = h0v * wp.x + h1v * wp.y;
    }
  }
  p = wave_red_sum(p);
  if (lane == 0) spre[n] = p;
}

__global__ void k_gate(const float* __restrict__ spre, const int* __restrict__ offs,
                       const int* __restrict__ cnt, const int* __restrict__ csr,
                       const float* __restrict__ cf, const float* __restrict__ dis,
                       const float* __restrict__ bp, float* __restrict__ gate) {
  int n = blockIdx.x * 256 + threadIdx.x;
  if (n >= N_NODES) return;
  float disn = dis[n];
  float s = bp[0] + disn * disn * spre[n];
  int st = offs[n], cn = cnt[n];
#pragma unroll 4
  for (int j = 0; j < cn; ++j) {
    s += cf[st + j] * spre[csr[st + j]];
  }
  gate[n] = tanhf(s);
}

// per-graph max & mean over contiguous 256-node segments; accumulate x1+x2+x3
__global__ __launch_bounds__(128) void k_readout(const unsigned short* __restrict__ h,
                                                 const float* __restrict__ gate,
                                                 float* __restrict__ xsum, int accum) {
  __shared__ float gl[256];
  int b = blockIdx.x, tid = threadIdx.x;
  for (int i = tid; i < 256; i += 128) gl[i] = gate[b * 256 + i];
  __syncthreads();
  if (tid >= NF) return;
  float mx = -1e30f, sm = 0.f;
  const unsigned short* hp = h + (size_t)b * 256 * NF + tid;
  for (int nn = 0; nn < 256; ++nn) {
    float v = bf2f(hp[(size_t)nn * NF]) * gl[nn];
    mx = fmaxf(mx, v);
    sm += v;
  }
  float mean = sm * (1.f / 256.f);
  if (accum) {
    xsum[b * 156 + tid] += mx;
    xsum[b * 156 + NF + tid] += mean;
  } else {
    xsum[b * 156 + tid] = mx;
    xsum[b * 156 + NF + tid] = mean;
  }
}

// g = relu(bn4((x1+x2+x3) @ fcg1_W + fcg1_b))
__global__ __launch_bounds__(128) void k_fcg(const float* __restrict__ xsum, const float* __restrict__ W,
                                             const float* __restrict__ bias, const float* __restrict__ bn,
                                             float* __restrict__ g) {
  __shared__ float xs[156];
  int b = blockIdx.x, tid = threadIdx.x;
  for (int i = tid; i < 156; i += 128) xs[i] = xsum[b * 156 + i];
  __syncthreads();
  float acc = bias[tid];
  for (int i = 0; i < 156; ++i) acc += xs[i] * W[i * 128 + tid];
  g[b * 128 + tid] = fmaxf(0.f, bn[tid] * BNR * acc + bn[128 + tid]);
}

// ---------------- protein branch ----------------
// Wt[i*384 + oc*3 + k] = c1W[oc*3000 + i*3 + k]
__global__ void k_transpose_w(const float* __restrict__ c1W, float* __restrict__ Wt) {
  int idx = blockIdx.x * 256 + threadIdx.x;
  if (idx >= 384000) return;
  int i = idx / 384;
  int r = idx - i * 384;
  int oc = r / 3, k = r - oc * 3;
  Wt[idx] = c1W[oc * 3000 + i * 3 + k];
}

// Wt2[(i*3+k)*64 + oc] = c2W[oc*384 + i*3 + k]   (64 oc, 128 i)
__global__ void k_transpose_w2(const float* __restrict__ c2W, float* __restrict__ Wt2) {
  int idx = blockIdx.x * 256 + threadIdx.x;
  if (idx >= 24576) return;
  int ik = idx >> 6, oc = idx & 63;
  Wt2[idx] = c2W[oc * 384 + ik];
}

// Wt3[(i*3+k)*32 + oc] = c3W[oc*192 + i*3 + k]   (32 oc, 64 i)
__global__ void k_transpose_w3(const float* __restrict__ c3W, float* __restrict__ Wt3) {
  int idx = blockIdx.x * 256 + threadIdx.x;
  if (idx >= 6144) return;
  int ik = idx >> 5, oc = idx & 31;
  Wt3[idx] = c3W[oc * 192 + ik];
}

// conv1 G build: grid 1024 = (b, vocab-half); 384 threads; tiny LDS -> high occupancy.
__global__ __launch_bounds__(384) void k_conv1g(const float* __restrict__ Wt, const int* __restrict__ target,
                                                float* __restrict__ Gbuf) {
  __shared__ int tg[1000];
  __shared__ int border[1000];
  __shared__ int cnt26[26], boff[27], cur26[26];
  int bb = blockIdx.x;
  int b = bb >> 1, vh = bb & 1;
  int tid = threadIdx.x;
  if (tid < 26) cnt26[tid] = 0;
  for (int i = tid; i < 1000; i += 384) tg[i] = target[b * 1000 + i];
  __syncthreads();
  for (int i = tid; i < 1000; i += 384) atomicAdd(&cnt26[tg[i]], 1);
  __syncthreads();
  if (tid == 0) {
    int run = 0;
    for (int v = 0; v < 26; ++v) { boff[v] = run; cur26[v] = run; run += cnt26[v]; }
    boff[26] = run;
  }
  __syncthreads();
  for (int i = tid; i < 1000; i += 384) {
    int v = tg[i];
    int slot = atomicAdd(&cur26[v], 1);
    border[slot] = i;
  }
  __syncthreads();
  int v0 = vh * 13, v1 = v0 + 13;
  for (int v = v0; v < v1; ++v) {
    int k0 = boff[v], k1 = boff[v + 1];
    float a0 = 0.f, a1 = 0.f, a2 = 0.f, a3 = 0.f;
    int k = k0;
#pragma unroll 2
    for (; k + 4 <= k1; k += 4) {
      int p0 = border[k];
      int p1 = border[k + 1];
      int p2 = border[k + 2];
      int p3 = border[k + 3];
      a0 += Wt[(size_t)p0 * 384 + tid];
      a1 += Wt[(size_t)p1 * 384 + tid];
      a2 += Wt[(size_t)p2 * 384 + tid];
      a3 += Wt[(size_t)p3 * 384 + tid];
    }
    for (; k < k1; ++k) a0 += Wt[(size_t)border[k] * 384 + tid];
    Gbuf[((size_t)b * 26 + v) * 384 + tid] = (a0 + a1) + (a2 + a3);
  }
}

// conv1 emb multiply: loads G from Gbuf (coalesced LDS stage), phase-3 math unchanged.
__global__ __launch_bounds__(512) void k_conv1e(const float* __restrict__ Gbuf,
                                                const float* __restrict__ emb, const float* __restrict__ c1b,
                                                const float* __restrict__ bnx, float* __restrict__ O) {
  __shared__ float G[26 * 384];
  __shared__ float el[26 * 132];
  int b = blockIdx.x, tid = threadIdx.x;
  for (int i = tid; i < 26 * 384; i += 512) G[i] = Gbuf[(size_t)b * (26 * 384) + i];
  for (int i = tid; i < 26 * 132; i += 512) {
    int v = i / 132, hp = i - v * 132;
    el[i] = (hp >= 1 && hp <= 128) ? emb[v * 128 + hp - 1] : 0.f;
  }
  __syncthreads();
  int oc = tid & 127, q = tid >> 7;
  int h0 = q * 32;
  float acc[32];
#pragma unroll
  for (int j = 0; j < 32; ++j) acc[j] = 0.f;
  for (int v = 0; v < 26; ++v) {
    float g0 = G[v * 384 + oc * 3 + 0];
    float g1 = G[v * 384 + oc * 3 + 1];
    float g2 = G[v * 384 + oc * 3 + 2];
    float4 buf[9];
    const float4* ep = reinterpret_cast<const float4*>(&el[v * 132 + h0]);
#pragma unroll
    for (int r = 0; r < 9; ++r) buf[r] = ep[r];
    const float* bf = reinterpret_cast<const float*>(buf);
#pragma unroll
    for (int j = 0; j < 32; ++j)
      acc[j] += g0 * bf[j] + g1 * bf[j + 1] + g2 * bf[j + 2];
  }
  float bia = c1b[oc];
  float sc = bnx[oc] * BNR, bt = bnx[128 + oc];
  float* outp = O + (size_t)b * 16384 + oc * 128 + h0;
#pragma unroll
  for (int j = 0; j < 32; ++j) acc[j] = fmaxf(0.f, sc * (acc[j] + bia) + bt);
#pragma unroll
  for (int j = 0; j < 8; ++j)
    *reinterpret_cast<float4*>(outp + 4 * j) =
        make_float4(acc[4 * j], acc[4 * j + 1], acc[4 * j + 2], acc[4 * j + 3]);
}

// conv2: h-split x2 (grid 1024); bf16 X slab [128][36] uints = 18.4KB.
// Window per i: 3x b128 (12 uints, 10 used) + 20 decode ops + 48 FMA.
// LDS instr count 5->3 per i: attacks the measured LDS-pipe bound.
__global__ __launch_bounds__(256) void k_conv2(const float* __restrict__ X, const float* __restrict__ Wt2,
                                               const float* __restrict__ bias, const float* __restrict__ bnx,
                                               float* __restrict__ O) {
  __shared__ unsigned xl[128 * 36];
  int bid = blockIdx.x;
  int b = bid >> 1, jh = bid & 1;
  int h_base = jh * 64;
  int tid = threadIdx.x;
  for (int t = tid; t < 128 * 36; t += 256) {
    int r = t / 36, u = t - r * 36;
    int f0 = h_base - 1 + 2 * u;            // slab position 2u holds feature h_base-1+2u
    int f1 = f0 + 1;
    float v0 = (f0 >= 0 && f0 < 128) ? X[(size_t)b * 16384 + r * 128 + f0] : 0.f;
    float v1 = (f1 >= 0 && f1 < 128) ? X[(size_t)b * 16384 + r * 128 + f1] : 0.f;
    xl[t] = f2bf_rn(v0) | (f2bf_rn(v1) << 16);
  }
  __syncthreads();
  int oc = tid & 63, q = tid >> 6;          // q 0..3, h-chunk of 16
  int p0 = q * 16;                           // window positions p0..p0+18
  int u0 = p0 >> 1;                          // uint start (multiple of 8 -> 16B aligned)
  float acc[16];
#pragma unroll
  for (int j = 0; j < 16; ++j) acc[j] = 0.f;
  const float* wp = Wt2 + oc;
  float w0 = wp[0], w1 = wp[64], w2 = wp[128];
  for (int i = 0; i < 128; ++i) {
    float nw0 = wp[(i * 3 + 3) * 64];
    float nw1 = wp[(i * 3 + 4) * 64];
    float nw2 = wp[(i * 3 + 5) * 64];
    uint4 ub[3];
    const uint4* xp = reinterpret_cast<const uint4*>(&xl[i * 36 + u0]);
    ub[0] = xp[0]; ub[1] = xp[1]; ub[2] = xp[2];
    const unsigned* uu = reinterpret_cast<const unsigned*>(ub);
    float bf[20];
#pragma unroll
    for (int m = 0; m < 10; ++m) {
      bf[2 * m]     = __uint_as_float(uu[m] << 16);
      bf[2 * m + 1] = __uint_as_float(uu[m] & 0xffff0000u);
    }
#pragma unroll
    for (int j = 0; j < 16; ++j)
      acc[j] += w0 * bf[j] + w1 * bf[j + 1] + w2 * bf[j + 2];
    w0 = nw0; w1 = nw1; w2 = nw2;
  }
  float bia = bias[oc], sc = bnx[oc] * BNR, bt = bnx[64 + oc];
  float* outp = O + (size_t)b * 8192 + oc * 128 + h_base + p0;
#pragma unroll
  for (int j = 0; j < 16; ++j) acc[j] = fmaxf(0.f, sc * (acc[j] + bia) + bt);
#pragma unroll
  for (int j = 0; j < 4; ++j)
    *reinterpret_cast<float4*>(outp + 4 * j) =
        make_float4(acc[4 * j], acc[4 * j + 1], acc[4 * j + 2], acc[4 * j + 3]);
}

// conv3: b128 bulk window reads; weights [i][k][oc] coalesced; i-unroll x2.
__global__ __launch_bounds__(256) void k_conv3(const float* __restrict__ X, const float* __restrict__ Wt3,
                                               const float* __restrict__ bias, const float* __restrict__ bnx,
                                               float* __restrict__ O) {
  __shared__ float xl[64 * 136];
  int b = blockIdx.x, tid = threadIdx.x;
  for (int i = tid; i < 64 * 32; i += 256) {
    int row = i >> 5, c4 = (i & 31) * 4;
    float4 v = *reinterpret_cast<const float4*>(X + (size_t)b * 8192 + row * 128 + c4);
    *reinterpret_cast<float4*>(&xl[row * 136 + 4 + c4]) = v;
  }
  if (tid < 64) { xl[tid * 136 + 3] = 0.f; xl[tid * 136 + 132] = 0.f; }
  __syncthreads();
  int oc = tid & 31, q = tid >> 5;  // 0..7
  int h0 = q * 16;
  float acc[16];
#pragma unroll
  for (int j = 0; j < 16; ++j) acc[j] = 0.f;
  const float* wp = Wt3 + oc;
  for (int i = 0; i < 64; i += 2) {
    float wA0 = wp[(i * 3 + 0) * 32];
    float wA1 = wp[(i * 3 + 1) * 32];
    float wA2 = wp[(i * 3 + 2) * 32];
    float wB0 = wp[(i * 3 + 3) * 32];
    float wB1 = wp[(i * 3 + 4) * 32];
    float wB2 = wp[(i * 3 + 5) * 32];
    float4 bufA[6], bufB[6];
    const float4* xpA = reinterpret_cast<const float4*>(&xl[i * 136 + h0]);
    const float4* xpB = reinterpret_cast<const float4*>(&xl[(i + 1) * 136 + h0]);
#pragma unroll
    for (int r = 0; r < 6; ++r) { bufA[r] = xpA[r]; bufB[r] = xpB[r]; }
    const float* bfA = reinterpret_cast<const float*>(bufA);
    const float* bfB = reinterpret_cast<const float*>(bufB);
#pragma unroll
    for (int j = 0; j < 16; ++j) {
      acc[j] += wA0 * bfA[3 + j] + wA1 * bfA[4 + j] + wA2 * bfA[5 + j];
      acc[j] += wB0 * bfB[3 + j] + wB1 * bfB[4 + j] + wB2 * bfB[5 + j];
    }
  }
  float bia = bias[oc], sc = bnx[oc] * BNR, bt = bnx[32 + oc];
  float* outp = O + (size_t)b * 4096 + oc * 128 + h0;
#pragma unroll
  for (int j = 0; j < 16; ++j) acc[j] = fmaxf(0.f, sc * (acc[j] + bia) + bt);
#pragma unroll
  for (int j = 0; j < 4; ++j)
    *reinterpret_cast<float4*>(outp + 4 * j) =
        make_float4(acc[4 * j], acc[4 * j + 1], acc[4 * j + 2], acc[4 * j + 3]);
}

// ---- fxt: [512,4096] @ [4096,128], K-split 8 ways for parallelism ----
__global__ __launch_bounds__(128) void k_fxt_part(const float* __restrict__ P, const float* __restrict__ W,
                                                  float* __restrict__ part) {
  __shared__ float pl[8 * 512];
  int bblk = blockIdx.x >> 3, kc = blockIdx.x & 7;
  int b0 = bblk * 8, tid = threadIdx.x;
  for (int i = tid; i < 8 * 512; i += 128) {
    int bb = i >> 9, k = i & 511;
    pl[i] = P[(size_t)(b0 + bb) * 4096 + kc * 512 + k];
  }
  __syncthreads();
  float acc[8] = {};
  const float* wp = W + (size_t)kc * 512 * 128 + tid;
  for (int k = 0; k < 512; ++k) {
    float w = wp[(size_t)k * 128];
#pragma unroll
    for (int bb = 0; bb < 8; ++bb) acc[bb] += pl[bb * 512 + k] * w;
  }
#pragma unroll
  for (int bb = 0; bb < 8; ++bb)
    part[((size_t)kc * 512 + b0 + bb) * 128 + tid] = acc[bb];
}

// xt = bn6(relu(sum_kc part + fxt_b))   (bn AFTER relu)
__global__ __launch_bounds__(256) void k_fxt_red(const float* __restrict__ part, const float* __restrict__ bias,
                                                 const float* __restrict__ bn, float* __restrict__ xt) {
  int idx = blockIdx.x * 256 + threadIdx.x;  // 512*128
  int j = idx & 127;
  float s = 0.f;
#pragma unroll
  for (int kc = 0; kc < 8; ++kc) s += part[(size_t)kc * 65536 + idx];
  xt[idx] = bn[j] * BNR * fmaxf(0.f, s + bias[j]) + bn[128 + j];
}

// xc1 = bn7(relu([g|xt] @ fc1W + fc1b)); grid 512 = (bblk 0..127)x(jb 0..3)
__global__ __launch_bounds__(256) void k_fc1(const float* __restrict__ g, const float* __restrict__ xt,
                                             const float* __restrict__ W, const float* __restrict__ bias,
                                             const float* __restrict__ bn, float* __restrict__ out) {
  __shared__ float al[4 * 256];
  int bblk = blockIdx.x >> 2, jb = blockIdx.x & 3;
  int b0 = bblk * 4, tid = threadIdx.x;
  int j = jb * 256 + tid;
  for (int i = tid; i < 4 * 256; i += 256) {
    int bb = i >> 8, c = i & 255;
    al[i] = (c < 128) ? g[(b0 + bb) * 128 + c] : xt[(b0 + bb) * 128 + c - 128];
  }
  __syncthreads();
  float acc[4] = {};
  for (int i = 0; i < 256; ++i) {
    float w = W[(size_t)i * 1024 + j];
#pragma unroll
    for (int bb = 0; bb < 4; ++bb) acc[bb] += al[bb * 256 + i] * w;
  }
  float bi = bias[j], sc = bn[j] * BNR, bt = bn[1024 + j];
#pragma unroll
  for (int bb = 0; bb < 4; ++bb)
    out[(size_t)(b0 + bb) * 1024 + j] = sc * fmaxf(0.f, acc[bb] + bi) + bt;
}

// xc2 = bn8(relu(xc1 @ fc2W + fc2b)); grid 256 = (bblk 0..127)x(jb 0..1)
__global__ __launch_bounds__(256) void k_fc2(const float* __restrict__ xc1, const float* __restrict__ W,
                                             const float* __restrict__ bias, const float* __restrict__ bn,
                                             float* __restrict__ out) {
  __shared__ float al[4 * 1024];
  int bblk = blockIdx.x >> 1, jb = blockIdx.x & 1;
  int b0 = bblk * 4, tid = threadIdx.x;
  int j = jb * 256 + tid;
  for (int i = tid; i < 4 * 1024; i += 256)
    al[i] = xc1[(size_t)(b0 + (i >> 10)) * 1024 + (i & 1023)];
  __syncthreads();
  float acc[4] = {};
  for (int i = 0; i < 1024; ++i) {
    float w = W[(size_t)i * 512 + j];
#pragma unroll
    for (int bb = 0; bb < 4; ++bb) acc[bb] += al[bb * 1024 + i] * w;
  }
  float bi = bias[j], sc = bn[j] * BNR, bt = bn[512 + j];
#pragma unroll
  for (int bb = 0; bb < 4; ++bb)
    out[(size_t)(b0 + bb) * 512 + j] = sc * fmaxf(0.f, acc[bb] + bi) + bt;
}

__global__ __launch_bounds__(256) void k_out(const float* __restrict__ xc2, const float* __restrict__ W,
                                             const float* __restrict__ ob, float* __restrict__ out) {
  __shared__ float red[4];
  int b = blockIdx.x, tid = threadIdx.x;
  float v = xc2[(size_t)b * 512 + tid] * W[tid] + xc2[(size_t)b * 512 + 256 + tid] * W[256 + tid];
  v = wave_red_sum(v);
  int wave = tid >> 6, lane = tid & 63;
  if (lane == 0) red[wave] = v;
  __syncthreads();
  if (tid == 0) out[b] = red[0] + red[1] + red[2] + red[3] + ob[0];
}

extern "C" void kernel_launch(void* const* d_in, const int* in_sizes, int n_in,
                              void* d_out, int out_size, void* d_ws, size_t ws_size,
                              hipStream_t stream) {
  (void)in_sizes; (void)n_in; (void)out_size; (void)ws_size;
  const float* x      = (const float*)d_in[0];
  const int*   eidx   = (const int*)d_in[1];
  const int*   src    = eidx;
  const int*   dst    = eidx + N_EDGES;
  const int*   target = (const int*)d_in[3];
  const float* W1 = (const float*)d_in[4];  const float* b1 = (const float*)d_in[5];
  const float* bn1 = (const float*)d_in[6]; const float* Wp1 = (const float*)d_in[7];
  const float* bp1 = (const float*)d_in[8];
  const float* W2 = (const float*)d_in[9];  const float* b2 = (const float*)d_in[10];
  const float* bn2 = (const float*)d_in[11]; const float* Wp2 = (const float*)d_in[12];
  const float* bp2 = (const float*)d_in[13];
  const float* W3 = (const float*)d_in[14]; const float* b3 = (const float*)d_in[15];
  const float* bn3 = (const float*)d_in[16]; const float* Wp3 = (const float*)d_in[17];
  const float* bp3 = (const float*)d_in[18];
  const float* fcg1_W = (const float*)d_in[19]; const float* fcg1_b = (const float*)d_in[20];
  const float* bn4 = (const float*)d_in[21];
  const float* emb = (const float*)d_in[22];
  const float* c1W = (const float*)d_in[23]; const float* c1b = (const float*)d_in[24];
  const float* bnx1 = (const float*)d_in[25];
  const float* c2W = (const float*)d_in[26]; const float* c2b = (const float*)d_in[27];
  const float* bnx2 = (const float*)d_in[28];
  const float* c3W = (const float*)d_in[29]; const float* c3b = (const float*)d_in[30];
  const float* bnx3 = (const float*)d_in[31];
  const float* fxt_W = (const float*)d_in[32]; const float* fxt_b = (const float*)d_in[33];
  const float* bn6 = (const float*)d_in[34];
  const float* fc1W = (const float*)d_in[35]; const float* fc1b = (const float*)d_in[36];
  const float* bn7 = (const float*)d_in[37];
  const float* fc2W = (const float*)d_in[38]; const float* fc2b = (const float*)d_in[39];
  const float* bn8 = (const float*)d_in[40];
  const float* outW = (const float*)d_in[41]; const float* outb = (const float*)d_in[42];

  char* ws = (char*)d_ws;
  size_t off = 0;
  auto alloc = [&](size_t bytes) -> void* {
    void* p = ws + off;
    off += (bytes + 255) & ~(size_t)255;
    return p;
  };
  float* dis   = (float*)alloc((size_t)N_NODES * 4);
  int*   cnt   = (int*)alloc((size_t)N_NODES * 4);
  int*   cursor= (int*)alloc((size_t)N_NODES * 4);
  int*   offs  = (int*)alloc((size_t)N_NODES * 4);
  int*   bsum  = (int*)alloc(1024);
  int*   csr   = (int*)alloc((size_t)N_EDGES * 4);
  float* cf    = (float*)alloc((size_t)N_EDGES * 4);
  float* h_a   = (float*)alloc((size_t)N_NODES * NF * 4);   // region; holds bf16 h rows (39 uints)
  float* h_b   = (float*)alloc((size_t)N_NODES * NF * 4);
  float* tbuf  = (float*)alloc((size_t)N_NODES * NF * 4);   // region; holds fp8 t (128B rows = 16.8MB)
  float* gate  = (float*)alloc((size_t)N_NODES * 4);
  float* spre  = (float*)alloc((size_t)N_NODES * 4);
  float* xsum  = (float*)alloc(512 * 156 * 4);
  float* gbuf  = (float*)alloc(512 * 128 * 4);
  float* xt    = (float*)alloc(512 * 128 * 4);
  float* xc1   = (float*)alloc(512 * 1024 * 4);
  float* xc2   = (float*)alloc(512 * 512 * 4);
  unsigned char*  t8  = (unsigned char*)tbuf;
  unsigned*       tu  = (unsigned*)tbuf;
  unsigned* ha_u = (unsigned*)h_a;  unsigned short* ha_s = (unsigned short*)h_a;
  unsigned* hb_u = (unsigned*)h_b;  unsigned short* hb_s = (unsigned short*)h_b;
  // protein-branch aliases (GNN big buffers are dead by then)
  float* O1 = h_a;                      // 512*128*128 = 33.5 MB <= 40.9 MB
  float* O2 = h_b;                      // 512*64*128  = 16.8 MB (written by conv2, after Gbuf dead)
  float* Gbuf = h_b;                    // 512*26*384  = 20.4 MB (conv1g->conv1e, dead before conv2)
  float* Wt = tbuf;                     // 1000*384    = 1.54 MB
  float* Wt2 = tbuf + 393216;           // 24576 floats (conv2 weights, i-major) + slack
  float* Wt3 = tbuf + 425984;           // 6144 floats (conv3 weights, i-major)
  float* P  = tbuf + 5242880;           // +20 MB: past fp8 t region; 512*32*128 = 8.4 MB (fits 40.9)
  float* fxt_part = h_a;                // 8*512*128 = 2 MB (O1 dead after conv2)

  hipMemsetAsync(cnt, 0, (size_t)N_NODES * 4, stream);
  hipMemsetAsync(cursor, 0, (size_t)N_NODES * 4, stream);

  k_count<<<N_EDGES / 256, 256, 0, stream>>>(dst, cnt);
  k_dis<<<N_NODES / 256, 256, 0, stream>>>(cnt, dis);
  k_scan1<<<N_NODES / 512, 512, 0, stream>>>(cnt, offs, bsum);
  k_scan2<<<1, 256, 0, stream>>>(bsum);
  k_scan3<<<N_NODES / 512, 512, 0, stream>>>(offs, bsum);
  k_fill<<<N_EDGES / 256, 256, 0, stream>>>(src, dst, offs, cursor, dis, csr, cf);

  // layer 1
  k_gemm_f32<<<N_NODES / 64, 256, 0, stream>>>(x, W1, t8);
  k_agg<<<N_NODES / 4, 256, 0, stream>>>(tu, offs, cnt, csr, cf, dis, b1, bn1, Wp1, ha_u, spre);
  k_gate<<<N_NODES / 256, 256, 0, stream>>>(spre, offs, cnt, csr, cf, dis, bp1, gate);
  k_readout<<<NB, 128, 0, stream>>>(ha_s, gate, xsum, 0);
  // layer 2
  k_gemm_bf16<<<N_NODES / 64, 256, 0, stream>>>(ha_s, gate, W2, t8);
  k_agg<<<N_NODES / 4, 256, 0, stream>>>(tu, offs, cnt, csr, cf, dis, b2, bn2, Wp2, hb_u, spre);
  k_gate<<<N_NODES / 256, 256, 0, stream>>>(spre, offs, cnt, csr, cf, dis, bp2, gate);
  k_readout<<<NB, 128, 0, stream>>>(hb_s, gate, xsum, 1);
  // layer 3
  k_gemm_bf16<<<N_NODES / 64, 256, 0, stream>>>(hb_s, gate, W3, t8);
  k_agg<<<N_NODES / 4, 256, 0, stream>>>(tu, offs, cnt, csr, cf, dis, b3, bn3, Wp3, ha_u, spre);
  k_gate<<<N_NODES / 256, 256, 0, stream>>>(spre, offs, cnt, csr, cf, dis, bp3, gate);
  k_readout<<<NB, 128, 0, stream>>>(ha_s, gate, xsum, 1);

  k_fcg<<<NB, 128, 0, stream>>>(xsum, fcg1_W, fcg1_b, bn4, gbuf);

  // protein branch (reuses h_a/h_b/tbuf regions — all GNN reads complete above)
  k_transpose_w<<<1500, 256, 0, stream>>>(c1W, Wt);
  k_transpose_w2<<<96, 256, 0, stream>>>(c2W, Wt2);
  k_transpose_w3<<<24, 256, 0, stream>>>(c3W, Wt3);
  k_conv1g<<<NB * 2, 384, 0, stream>>>(Wt, target, Gbuf);
  k_conv1e<<<NB, 512, 0, stream>>>(Gbuf, emb, c1b, bnx1, O1);
  k_conv2<<<NB * 2, 256, 0, stream>>>(O1, Wt2, c2b, bnx2, O2);
  k_conv3<<<NB, 256, 0, stream>>>(O2, Wt3, c3b, bnx3, P);
  // O1 (h_a) is dead after conv2 -> reuse for fxt partials
  k_fxt_part<<<512, 128, 0, stream>>>(P, fxt_W, fxt_part);
  k_fxt_red<<<256, 256, 0, stream>>>(fxt_part, fxt_b, bn6, xt);

  k_fc1<<<512, 256, 0, stream>>>(gbuf, xt, fc1W, fc1b, bn7, xc1);
  k_fc2<<<256, 256, 0, stream>>>(xc1, fc2W, fc2b, bn8, xc2);
  k_out<<<NB, 256, 0, stream>>>(xc2, outW, outb, (float*)d_out);
}

// Round 23
// 725.990 us; speedup vs baseline: 1.0238x; 1.0238x over previous
//
#include <hip/hip_runtime.h>
#include <hip/hip_bf16.h>
#include <cstddef>

#define N_NODES 131072
#define N_EDGES 1048576
#define NF 78
#define NB 512
#define BNR 0.9999950000374996f  // 1/sqrt(1+1e-5)

typedef float v2f __attribute__((ext_vector_type(2)));

__device__ __forceinline__ float wave_red_sum(float v) {
  for (int off = 32; off > 0; off >>= 1) v += __shfl_down(v, off);
  return v;
}

__device__ __forceinline__ float bf2f(unsigned short u) {
  return __uint_as_float(((unsigned)u) << 16);
}

__device__ __forceinline__ unsigned f2bf_rn(float x) {  // round-to-nearest-even bf16 bits
  unsigned u = __float_as_uint(x);
  return (u + 0x7fffu + ((u >> 16) & 1u)) >> 16;
}

__device__ __forceinline__ unsigned char f2fp8(float x) {  // OCP e4m3 via HW cvt
  int p = __builtin_amdgcn_cvt_pk_fp8_f32(x, x, 0, false);
  return (unsigned char)(p & 0xff);
}

// ---------------- graph setup ----------------
__global__ void k_count(const int* __restrict__ dst, int* __restrict__ cnt) {
  int e = blockIdx.x * 256 + threadIdx.x;
  if (e < N_EDGES) atomicAdd(&cnt[dst[e]], 1);
}

__global__ void k_dis(const int* __restrict__ cnt, float* __restrict__ dis) {
  int n = blockIdx.x * 256 + threadIdx.x;
  if (n < N_NODES) dis[n] = rsqrtf(1.0f + (float)cnt[n]);
}

__global__ void k_scan1(const int* __restrict__ cnt, int* __restrict__ offs, int* __restrict__ bsum) {
  __shared__ int s[512];
  int gid = blockIdx.x * 512 + threadIdx.x;
  int v = cnt[gid];
  s[threadIdx.x] = v; __syncthreads();
  for (int off = 1; off < 512; off <<= 1) {
    int t = (threadIdx.x >= off) ? s[threadIdx.x - off] : 0;
    __syncthreads();
    s[threadIdx.x] += t;
    __syncthreads();
  }
  offs[gid] = s[threadIdx.x] - v;               // exclusive
  if (threadIdx.x == 511) bsum[blockIdx.x] = s[511];
}

__global__ void k_scan2(int* __restrict__ bsum) {  // 1 block, 256 threads
  __shared__ int s[256];
  int v = bsum[threadIdx.x];
  s[threadIdx.x] = v; __syncthreads();
  for (int off = 1; off < 256; off <<= 1) {
    int t = (threadIdx.x >= off) ? s[threadIdx.x - off] : 0;
    __syncthreads();
    s[threadIdx.x] += t;
    __syncthreads();
  }
  bsum[threadIdx.x] = s[threadIdx.x] - v;       // exclusive
}

__global__ void k_scan3(int* __restrict__ offs, const int* __restrict__ bsum) {
  int gid = blockIdx.x * 512 + threadIdx.x;
  offs[gid] += bsum[blockIdx.x];
}

__global__ void k_fill(const int* __restrict__ src, const int* __restrict__ dst,
                       const int* __restrict__ offs, int* __restrict__ cursor,
                       const float* __restrict__ dis, int* __restrict__ csr,
                       float* __restrict__ cf) {
  int e = blockIdx.x * 256 + threadIdx.x;
  if (e < N_EDGES) {
    int s = src[e], d = dst[e];
    int pos = offs[d] + atomicAdd(&cursor[d], 1);
    csr[pos] = s;
    cf[pos] = dis[s] * dis[d];
  }
}

// ---------------- GCN layer ----------------
// t = h @ W  (layer 1, f32 input, no gate), output fp8 e4m3, row stride 128B
__global__ __launch_bounds__(256) void k_gemm_f32(const float* __restrict__ h,
                                                  const float* __restrict__ W,
                                                  unsigned char* __restrict__ t8) {
  __shared__ float hs[64 * NF];
  __shared__ float Ws[NF * NF];
  int n0 = blockIdx.x * 64;
  int tid = threadIdx.x;
  for (int i = tid; i < NF * NF; i += 256) Ws[i] = W[i];
  for (int i = tid; i < 64 * NF; i += 256) hs[i] = h[(size_t)n0 * NF + i];
  __syncthreads();
  int rg = tid >> 4, cg = tid & 15;
  int r0 = rg * 4, c0 = cg * 5;
  float acc[4][5] = {};
  for (int k = 0; k < NF; ++k) {
    float wv[5];
#pragma unroll
    for (int j = 0; j < 5; ++j) wv[j] = (c0 + j < NF) ? Ws[k * NF + c0 + j] : 0.f;
#pragma unroll
    for (int i = 0; i < 4; ++i) {
      float hv = hs[(r0 + i) * NF + k];
#pragma unroll
      for (int j = 0; j < 5; ++j) acc[i][j] += hv * wv[j];
    }
  }
  for (int i = 0; i < 4; ++i)
    for (int j = 0; j < 5; ++j) {
      int c = c0 + j;
      if (c < NF) t8[(size_t)(n0 + r0 + i) * 128 + c] = f2fp8(acc[i][j]);
    }
}

// t = (h .* gate) @ W  (layers 2,3; h bf16), output fp8
__global__ __launch_bounds__(256) void k_gemm_bf16(const unsigned short* __restrict__ h,
                                                   const float* __restrict__ gate,
                                                   const float* __restrict__ W,
                                                   unsigned char* __restrict__ t8) {
  __shared__ float hs[64 * NF];
  __shared__ float Ws[NF * NF];
  int n0 = blockIdx.x * 64;
  int tid = threadIdx.x;
  for (int i = tid; i < NF * NF; i += 256) Ws[i] = W[i];
  for (int i = tid; i < 64 * NF; i += 256) {
    int r = i / NF;
    hs[i] = bf2f(h[(size_t)n0 * NF + i]) * gate[n0 + r];
  }
  __syncthreads();
  int rg = tid >> 4, cg = tid & 15;
  int r0 = rg * 4, c0 = cg * 5;
  float acc[4][5] = {};
  for (int k = 0; k < NF; ++k) {
    float wv[5];
#pragma unroll
    for (int j = 0; j < 5; ++j) wv[j] = (c0 + j < NF) ? Ws[k * NF + c0 + j] : 0.f;
#pragma unroll
    for (int i = 0; i < 4; ++i) {
      float hv = hs[(r0 + i) * NF + k];
#pragma unroll
      for (int j = 0; j < 5; ++j) acc[i][j] += hv * wv[j];
    }
  }
  for (int i = 0; i < 4; ++i)
    for (int j = 0; j < 5; ++j) {
      int c = c0 + j;
      if (c < NF) t8[(size_t)(n0 + r0 + i) * 128 + c] = f2fp8(acc[i][j]);
    }
}

// out = relu(bn(agg + t*selfc + b)); also spre = out . Wp  (one wave per node)
// 3-slot gather: lanes split into 3 groups of 20; each group handles one edge/iter.
__global__ __launch_bounds__(256) void k_agg(const unsigned* __restrict__ t32, const int* __restrict__ offs,
                                             const int* __restrict__ cnt, const int* __restrict__ csr,
                                             const float* __restrict__ cf, const float* __restrict__ dis,
                                             const float* __restrict__ bias, const float* __restrict__ bn,
                                             const float* __restrict__ Wp,
                                             unsigned* __restrict__ hout, float* __restrict__ spre) {
  __shared__ int   sIdxL[4 * 68];
  __shared__ float sCoefL[4 * 68];
  int wave = threadIdx.x >> 6, lane = threadIdx.x & 63;
  int n = blockIdx.x * 4 + wave;
  float disn = dis[n];
  int st = offs[n], cn = cnt[n];
  int cn1 = cn < 64 ? cn : 64;
  int base = wave * 68;
  if (lane < cn1) {
    int s = csr[st + lane];
    sIdxL[base + lane] = s * 32;          // uint stride 32 (128B rows)
    sCoefL[base + lane] = cf[st + lane];
  }
  if (lane < 3) {                          // pad 3 entries past cn1
    sIdxL[base + cn1 + lane] = 0;
    sCoefL[base + cn1 + lane] = 0.f;
  }
  int slot = lane / 20;                    // 0,1,2 active; 3 = lanes 60-63 (zero coef)
  int li = lane - slot * 20;               // 0..19
  float selfc = disn * disn;
  float a0 = 0.f, a1 = 0.f, a2 = 0.f, a3 = 0.f;
  if (slot == 0) {
    unsigned u = t32[(size_t)n * 32 + li];
    v2f f01 = __builtin_amdgcn_cvt_pk_f32_fp8((int)u, false);
    v2f f23 = __builtin_amdgcn_cvt_pk_f32_fp8((int)u, true);
    a0 = f01[0] * selfc; a1 = f01[1] * selfc;
    a2 = f23[0] * selfc; a3 = f23[1] * selfc;
  }
#pragma unroll 2
  for (int j = 0; j < cn1; j += 3) {
    int idx = sIdxL[base + j + slot];      // slot 3 reads pad (discarded, coef 0)
    float c = (slot < 3) ? sCoefL[base + j + slot] : 0.f;
    unsigned u = t32[idx + li];
    v2f f01 = __builtin_amdgcn_cvt_pk_f32_fp8((int)u, false);
    v2f f23 = __builtin_amdgcn_cvt_pk_f32_fp8((int)u, true);
    a0 += c * f01[0]; a1 += c * f01[1];
    a2 += c * f23[0]; a3 += c * f23[1];
  }
  for (int j = 64; j < cn; ++j) {          // safety tail (slot 0 lanes only)
    if (slot == 0) {
      int sb = csr[st + j] * 32; float c = cf[st + j];
      unsigned u = t32[sb + li];
      v2f f01 = __builtin_amdgcn_cvt_pk_f32_fp8((int)u, false);
      v2f f23 = __builtin_amdgcn_cvt_pk_f32_fp8((int)u, true);
      a0 += c * f01[0]; a1 += c * f01[1];
      a2 += c * f23[0]; a3 += c * f23[1];
    }
  }
  // merge slots: lanes 0-19 accumulate from lanes +20 and +40
  a0 += __shfl(a0, lane + 20) + __shfl(a0, lane + 40);
  a1 += __shfl(a1, lane + 20) + __shfl(a1, lane + 40);
  a2 += __shfl(a2, lane + 20) + __shfl(a2, lane + 40);
  a3 += __shfl(a3, lane + 20) + __shfl(a3, lane + 40);
  float p = 0.f;
  if (lane < 20) {
    int f0 = 4 * lane;
    float h0v, h1v, h2v, h3v;
    if (lane < 19) {
      float4 bi = *reinterpret_cast<const float4*>(bias + f0);
      float4 gm = *reinterpret_cast<const float4*>(bn + f0);
      float2 btA = *reinterpret_cast<const float2*>(bn + NF + f0);
      float2 btB = *reinterpret_cast<const float2*>(bn + NF + f0 + 2);
      float4 wp = *reinterpret_cast<const float4*>(Wp + f0);
      h0v = fmaxf(0.f, gm.x * BNR * (a0 + bi.x) + btA.x);
      h1v = fmaxf(0.f, gm.y * BNR * (a1 + bi.y) + btA.y);
      h2v = fmaxf(0.f, gm.z * BNR * (a2 + bi.z) + btB.x);
      h3v = fmaxf(0.f, gm.w * BNR * (a3 + bi.w) + btB.y);
      hout[(size_t)n * 39 + 2 * lane]     = f2bf_rn(h0v) | (f2bf_rn(h1v) << 16);
      hout[(size_t)n * 39 + 2 * lane + 1] = f2bf_rn(h2v) | (f2bf_rn(h3v) << 16);
      p = h0v * wp.x + h1v * wp.y + h2v * wp.z + h3v * wp.w;
    } else {  // features 76,77 only
      float2 bi = *reinterpret_cast<const float2*>(bias + 76);
      float2 gm = *reinterpret_cast<const float2*>(bn + 76);
      float2 bt = *reinterpret_cast<const float2*>(bn + NF + 76);
      float2 wp = *reinterpret_cast<const float2*>(Wp + 76);
      h0v = fmaxf(0.f, gm.x * BNR * (a0 + bi.x) + bt.x);
      h1v = fmaxf(0.f, gm.y * BNR * (a1 + bi.y) + bt.y);
      hout[(size_t)n * 39 + 38] = f2bf_rn(h0v) | (f2bf_rn(h1v) << 16);
      p = h0v * wp.x + h1v * wp.y;
    }
  }
  p = wave_red_sum(p);
  if (lane == 0) spre[n] = p;
}

__global__ void k_gate(const float* __restrict__ spre, const int* __restrict__ offs,
                       const int* __restrict__ cnt, const int* __restrict__ csr,
                       const float* __restrict__ cf, const float* __restrict__ dis,
                       const float* __restrict__ bp, float* __restrict__ gate) {
  int n = blockIdx.x * 256 + threadIdx.x;
  if (n >= N_NODES) return;
  float disn = dis[n];
  float s = bp[0] + disn * disn * spre[n];
  int st = offs[n], cn = cnt[n];
#pragma unroll 4
  for (int j = 0; j < cn; ++j) {
    s += cf[st + j] * spre[csr[st + j]];
  }
  gate[n] = tanhf(s);
}

// per-graph max & mean over contiguous 256-node segments; accumulate x1+x2+x3
__global__ __launch_bounds__(128) void k_readout(const unsigned short* __restrict__ h,
                                                 const float* __restrict__ gate,
                                                 float* __restrict__ xsum, int accum) {
  __shared__ float gl[256];
  int b = blockIdx.x, tid = threadIdx.x;
  for (int i = tid; i < 256; i += 128) gl[i] = gate[b * 256 + i];
  __syncthreads();
  if (tid >= NF) return;
  float mx = -1e30f, sm = 0.f;
  const unsigned short* hp = h + (size_t)b * 256 * NF + tid;
  for (int nn = 0; nn < 256; ++nn) {
    float v = bf2f(hp[(size_t)nn * NF]) * gl[nn];
    mx = fmaxf(mx, v);
    sm += v;
  }
  float mean = sm * (1.f / 256.f);
  if (accum) {
    xsum[b * 156 + tid] += mx;
    xsum[b * 156 + NF + tid] += mean;
  } else {
    xsum[b * 156 + tid] = mx;
    xsum[b * 156 + NF + tid] = mean;
  }
}

// g = relu(bn4((x1+x2+x3) @ fcg1_W + fcg1_b))
__global__ __launch_bounds__(128) void k_fcg(const float* __restrict__ xsum, const float* __restrict__ W,
                                             const float* __restrict__ bias, const float* __restrict__ bn,
                                             float* __restrict__ g) {
  __shared__ float xs[156];
  int b = blockIdx.x, tid = threadIdx.x;
  for (int i = tid; i < 156; i += 128) xs[i] = xsum[b * 156 + i];
  __syncthreads();
  float acc = bias[tid];
  for (int i = 0; i < 156; ++i) acc += xs[i] * W[i * 128 + tid];
  g[b * 128 + tid] = fmaxf(0.f, bn[tid] * BNR * acc + bn[128 + tid]);
}

// ---------------- protein branch ----------------
// Wt[i*384 + oc*3 + k] = c1W[oc*3000 + i*3 + k]
__global__ void k_transpose_w(const float* __restrict__ c1W, float* __restrict__ Wt) {
  int idx = blockIdx.x * 256 + threadIdx.x;
  if (idx >= 384000) return;
  int i = idx / 384;
  int r = idx - i * 384;
  int oc = r / 3, k = r - oc * 3;
  Wt[idx] = c1W[oc * 3000 + i * 3 + k];
}

// Wt2[(i*3+k)*64 + oc] = c2W[oc*384 + i*3 + k]   (64 oc, 128 i)
__global__ void k_transpose_w2(const float* __restrict__ c2W, float* __restrict__ Wt2) {
  int idx = blockIdx.x * 256 + threadIdx.x;
  if (idx >= 24576) return;
  int ik = idx >> 6, oc = idx & 63;
  Wt2[idx] = c2W[oc * 384 + ik];
}

// Wt3[(i*3+k)*32 + oc] = c3W[oc*192 + i*3 + k]   (32 oc, 64 i)
__global__ void k_transpose_w3(const float* __restrict__ c3W, float* __restrict__ Wt3) {
  int idx = blockIdx.x * 256 + threadIdx.x;
  if (idx >= 6144) return;
  int ik = idx >> 5, oc = idx & 31;
  Wt3[idx] = c3W[oc * 192 + ik];
}

// conv1 G build: grid 1024 = (b, vocab-half); 384 threads; tiny LDS -> high occupancy.
__global__ __launch_bounds__(384) void k_conv1g(const float* __restrict__ Wt, const int* __restrict__ target,
                                                float* __restrict__ Gbuf) {
  __shared__ int tg[1000];
  __shared__ int border[1000];
  __shared__ int cnt26[26], boff[27], cur26[26];
  int bb = blockIdx.x;
  int b = bb >> 1, vh = bb & 1;
  int tid = threadIdx.x;
  if (tid < 26) cnt26[tid] = 0;
  for (int i = tid; i < 1000; i += 384) tg[i] = target[b * 1000 + i];
  __syncthreads();
  for (int i = tid; i < 1000; i += 384) atomicAdd(&cnt26[tg[i]], 1);
  __syncthreads();
  if (tid == 0) {
    int run = 0;
    for (int v = 0; v < 26; ++v) { boff[v] = run; cur26[v] = run; run += cnt26[v]; }
    boff[26] = run;
  }
  __syncthreads();
  for (int i = tid; i < 1000; i += 384) {
    int v = tg[i];
    int slot = atomicAdd(&cur26[v], 1);
    border[slot] = i;
  }
  __syncthreads();
  int v0 = vh * 13, v1 = v0 + 13;
  for (int v = v0; v < v1; ++v) {
    int k0 = boff[v], k1 = boff[v + 1];
    float a0 = 0.f, a1 = 0.f, a2 = 0.f, a3 = 0.f;
    int k = k0;
#pragma unroll 2
    for (; k + 4 <= k1; k += 4) {
      int p0 = border[k];
      int p1 = border[k + 1];
      int p2 = border[k + 2];
      int p3 = border[k + 3];
      a0 += Wt[(size_t)p0 * 384 + tid];
      a1 += Wt[(size_t)p1 * 384 + tid];
      a2 += Wt[(size_t)p2 * 384 + tid];
      a3 += Wt[(size_t)p3 * 384 + tid];
    }
    for (; k < k1; ++k) a0 += Wt[(size_t)border[k] * 384 + tid];
    Gbuf[((size_t)b * 26 + v) * 384 + tid] = (a0 + a1) + (a2 + a3);
  }
}

// conv1 emb multiply: loads G from Gbuf (coalesced LDS stage), phase-3 math unchanged.
__global__ __launch_bounds__(512) void k_conv1e(const float* __restrict__ Gbuf,
                                                const float* __restrict__ emb, const float* __restrict__ c1b,
                                                const float* __restrict__ bnx, float* __restrict__ O) {
  __shared__ float G[26 * 384];
  __shared__ float el[26 * 132];
  int b = blockIdx.x, tid = threadIdx.x;
  for (int i = tid; i < 26 * 384; i += 512) G[i] = Gbuf[(size_t)b * (26 * 384) + i];
  for (int i = tid; i < 26 * 132; i += 512) {
    int v = i / 132, hp = i - v * 132;
    el[i] = (hp >= 1 && hp <= 128) ? emb[v * 128 + hp - 1] : 0.f;
  }
  __syncthreads();
  int oc = tid & 127, q = tid >> 7;
  int h0 = q * 32;
  float acc[32];
#pragma unroll
  for (int j = 0; j < 32; ++j) acc[j] = 0.f;
  for (int v = 0; v < 26; ++v) {
    float g0 = G[v * 384 + oc * 3 + 0];
    float g1 = G[v * 384 + oc * 3 + 1];
    float g2 = G[v * 384 + oc * 3 + 2];
    float4 buf[9];
    const float4* ep = reinterpret_cast<const float4*>(&el[v * 132 + h0]);
#pragma unroll
    for (int r = 0; r < 9; ++r) buf[r] = ep[r];
    const float* bf = reinterpret_cast<const float*>(buf);
#pragma unroll
    for (int j = 0; j < 32; ++j)
      acc[j] += g0 * bf[j] + g1 * bf[j + 1] + g2 * bf[j + 2];
  }
  float bia = c1b[oc];
  float sc = bnx[oc] * BNR, bt = bnx[128 + oc];
  float* outp = O + (size_t)b * 16384 + oc * 128 + h0;
#pragma unroll
  for (int j = 0; j < 32; ++j) acc[j] = fmaxf(0.f, sc * (acc[j] + bia) + bt);
#pragma unroll
  for (int j = 0; j < 8; ++j)
    *reinterpret_cast<float4*>(outp + 4 * j) =
        make_float4(acc[4 * j], acc[4 * j + 1], acc[4 * j + 2], acc[4 * j + 3]);
}

// conv2: h-split x2 (grid 1024), 34.8KB f32 slab -> 4 blocks/CU, coalesced weights,
// software-pipelined weight prefetch.
__global__ __launch_bounds__(256) void k_conv2(const float* __restrict__ X, const float* __restrict__ Wt2,
                                               const float* __restrict__ bias, const float* __restrict__ bnx,
                                               float* __restrict__ O) {
  __shared__ float xl[128 * 68];
  int bid = blockIdx.x;
  int b = bid >> 1, jh = bid & 1;
  int h_base = jh * 64;
  int tid = threadIdx.x;
  for (int t = tid; t < 128 * 68; t += 256) {
    int r = t / 68, p = t - r * 68;
    int f = h_base - 1 + p;                     // feature index; pos p holds f
    xl[t] = (f >= 0 && f < 128) ? X[(size_t)b * 16384 + r * 128 + f] : 0.f;
  }
  __syncthreads();
  int oc = tid & 63, q = tid >> 6;              // q 0..3, h-chunk of 16
  int p0 = q * 16;
  float acc[16];
#pragma unroll
  for (int j = 0; j < 16; ++j) acc[j] = 0.f;
  const float* wp = Wt2 + oc;
  float w0 = wp[0], w1 = wp[64], w2 = wp[128];
  for (int i = 0; i < 128; ++i) {
    float nw0 = wp[(i * 3 + 3) * 64];
    float nw1 = wp[(i * 3 + 4) * 64];
    float nw2 = wp[(i * 3 + 5) * 64];
    float4 buf[5];
    const float4* xp = reinterpret_cast<const float4*>(&xl[i * 68 + p0]);
#pragma unroll
    for (int r = 0; r < 5; ++r) buf[r] = xp[r];
    const float* bf = reinterpret_cast<const float*>(buf);
#pragma unroll
    for (int j = 0; j < 16; ++j)
      acc[j] += w0 * bf[j] + w1 * bf[j + 1] + w2 * bf[j + 2];
    w0 = nw0; w1 = nw1; w2 = nw2;
  }
  float bia = bias[oc], sc = bnx[oc] * BNR, bt = bnx[64 + oc];
  float* outp = O + (size_t)b * 8192 + oc * 128 + h_base + p0;
#pragma unroll
  for (int j = 0; j < 16; ++j) acc[j] = fmaxf(0.f, sc * (acc[j] + bia) + bt);
#pragma unroll
  for (int j = 0; j < 4; ++j)
    *reinterpret_cast<float4*>(outp + 4 * j) =
        make_float4(acc[4 * j], acc[4 * j + 1], acc[4 * j + 2], acc[4 * j + 3]);
}

// conv3: b128 bulk window reads; weights [i][k][oc] coalesced; i-unroll x2.
__global__ __launch_bounds__(256) void k_conv3(const float* __restrict__ X, const float* __restrict__ Wt3,
                                               const float* __restrict__ bias, const float* __restrict__ bnx,
                                               float* __restrict__ O) {
  __shared__ float xl[64 * 136];
  int b = blockIdx.x, tid = threadIdx.x;
  for (int i = tid; i < 64 * 32; i += 256) {
    int row = i >> 5, c4 = (i & 31) * 4;
    float4 v = *reinterpret_cast<const float4*>(X + (size_t)b * 8192 + row * 128 + c4);
    *reinterpret_cast<float4*>(&xl[row * 136 + 4 + c4]) = v;
  }
  if (tid < 64) { xl[tid * 136 + 3] = 0.f; xl[tid * 136 + 132] = 0.f; }
  __syncthreads();
  int oc = tid & 31, q = tid >> 5;  // 0..7
  int h0 = q * 16;
  float acc[16];
#pragma unroll
  for (int j = 0; j < 16; ++j) acc[j] = 0.f;
  const float* wp = Wt3 + oc;
  for (int i = 0; i < 64; i += 2) {
    float wA0 = wp[(i * 3 + 0) * 32];
    float wA1 = wp[(i * 3 + 1) * 32];
    float wA2 = wp[(i * 3 + 2) * 32];
    float wB0 = wp[(i * 3 + 3) * 32];
    float wB1 = wp[(i * 3 + 4) * 32];
    float wB2 = wp[(i * 3 + 5) * 32];
    float4 bufA[6], bufB[6];
    const float4* xpA = reinterpret_cast<const float4*>(&xl[i * 136 + h0]);
    const float4* xpB = reinterpret_cast<const float4*>(&xl[(i + 1) * 136 + h0]);
#pragma unroll
    for (int r = 0; r < 6; ++r) { bufA[r] = xpA[r]; bufB[r] = xpB[r]; }
    const float* bfA = reinterpret_cast<const float*>(bufA);
    const float* bfB = reinterpret_cast<const float*>(bufB);
#pragma unroll
    for (int j = 0; j < 16; ++j) {
      acc[j] += wA0 * bfA[3 + j] + wA1 * bfA[4 + j] + wA2 * bfA[5 + j];
      acc[j] += wB0 * bfB[3 + j] + wB1 * bfB[4 + j] + wB2 * bfB[5 + j];
    }
  }
  float bia = bias[oc], sc = bnx[oc] * BNR, bt = bnx[32 + oc];
  float* outp = O + (size_t)b * 4096 + oc * 128 + h0;
#pragma unroll
  for (int j = 0; j < 16; ++j) acc[j] = fmaxf(0.f, sc * (acc[j] + bia) + bt);
#pragma unroll
  for (int j = 0; j < 4; ++j)
    *reinterpret_cast<float4*>(outp + 4 * j) =
        make_float4(acc[4 * j], acc[4 * j + 1], acc[4 * j + 2], acc[4 * j + 3]);
}

// ---- fxt: [512,4096] @ [4096,128], K-split 8 ways for parallelism ----
__global__ __launch_bounds__(128) void k_fxt_part(const float* __restrict__ P, const float* __restrict__ W,
                                                  float* __restrict__ part) {
  __shared__ float pl[8 * 512];
  int bblk = blockIdx.x >> 3, kc = blockIdx.x & 7;
  int b0 = bblk * 8, tid = threadIdx.x;
  for (int i = tid; i < 8 * 512; i += 128) {
    int bb = i >> 9, k = i & 511;
    pl[i] = P[(size_t)(b0 + bb) * 4096 + kc * 512 + k];
  }
  __syncthreads();
  float acc[8] = {};
  const float* wp = W + (size_t)kc * 512 * 128 + tid;
  for (int k = 0; k < 512; ++k) {
    float w = wp[(size_t)k * 128];
#pragma unroll
    for (int bb = 0; bb < 8; ++bb) acc[bb] += pl[bb * 512 + k] * w;
  }
#pragma unroll
  for (int bb = 0; bb < 8; ++bb)
    part[((size_t)kc * 512 + b0 + bb) * 128 + tid] = acc[bb];
}

// xt = bn6(relu(sum_kc part + fxt_b))   (bn AFTER relu)
__global__ __launch_bounds__(256) void k_fxt_red(const float* __restrict__ part, const float* __restrict__ bias,
                                                 const float* __restrict__ bn, float* __restrict__ xt) {
  int idx = blockIdx.x * 256 + threadIdx.x;  // 512*128
  int j = idx & 127;
  float s = 0.f;
#pragma unroll
  for (int kc = 0; kc < 8; ++kc) s += part[(size_t)kc * 65536 + idx];
  xt[idx] = bn[j] * BNR * fmaxf(0.f, s + bias[j]) + bn[128 + j];
}

// xc1 = bn7(relu([g|xt] @ fc1W + fc1b)); grid 512 = (bblk 0..127)x(jb 0..3)
__global__ __launch_bounds__(256) void k_fc1(const float* __restrict__ g, const float* __restrict__ xt,
                                             const float* __restrict__ W, const float* __restrict__ bias,
                                             const float* __restrict__ bn, float* __restrict__ out) {
  __shared__ float al[4 * 256];
  int bblk = blockIdx.x >> 2, jb = blockIdx.x & 3;
  int b0 = bblk * 4, tid = threadIdx.x;
  int j = jb * 256 + tid;
  for (int i = tid; i < 4 * 256; i += 256) {
    int bb = i >> 8, c = i & 255;
    al[i] = (c < 128) ? g[(b0 + bb) * 128 + c] : xt[(b0 + bb) * 128 + c - 128];
  }
  __syncthreads();
  float acc[4] = {};
  for (int i = 0; i < 256; ++i) {
    float w = W[(size_t)i * 1024 + j];
#pragma unroll
    for (int bb = 0; bb < 4; ++bb) acc[bb] += al[bb * 256 + i] * w;
  }
  float bi = bias[j], sc = bn[j] * BNR, bt = bn[1024 + j];
#pragma unroll
  for (int bb = 0; bb < 4; ++bb)
    out[(size_t)(b0 + bb) * 1024 + j] = sc * fmaxf(0.f, acc[bb] + bi) + bt;
}

// xc2 = bn8(relu(xc1 @ fc2W + fc2b)); grid 256 = (bblk 0..127)x(jb 0..1)
__global__ __launch_bounds__(256) void k_fc2(const float* __restrict__ xc1, const float* __restrict__ W,
                                             const float* __restrict__ bias, const float* __restrict__ bn,
                                             float* __restrict__ out) {
  __shared__ float al[4 * 1024];
  int bblk = blockIdx.x >> 1, jb = blockIdx.x & 1;
  int b0 = bblk * 4, tid = threadIdx.x;
  int j = jb * 256 + tid;
  for (int i = tid; i < 4 * 1024; i += 256)
    al[i] = xc1[(size_t)(b0 + (i >> 10)) * 1024 + (i & 1023)];
  __syncthreads();
  float acc[4] = {};
  for (int i = 0; i < 1024; ++i) {
    float w = W[(size_t)i * 512 + j];
#pragma unroll
    for (int bb = 0; bb < 4; ++bb) acc[bb] += al[bb * 1024 + i] * w;
  }
  float bi = bias[j], sc = bn[j] * BNR, bt = bn[512 + j];
#pragma unroll
  for (int bb = 0; bb < 4; ++bb)
    out[(size_t)(b0 + bb) * 512 + j] = sc * fmaxf(0.f, acc[bb] + bi) + bt;
}

__global__ __launch_bounds__(256) void k_out(const float* __restrict__ xc2, const float* __restrict__ W,
                                             const float* __restrict__ ob, float* __restrict__ out) {
  __shared__ float red[4];
  int b = blockIdx.x, tid = threadIdx.x;
  float v = xc2[(size_t)b * 512 + tid] * W[tid] + xc2[(size_t)b * 512 + 256 + tid] * W[256 + tid];
  v = wave_red_sum(v);
  int wave = tid >> 6, lane = tid & 63;
  if (lane == 0) red[wave] = v;
  __syncthreads();
  if (tid == 0) out[b] = red[0] + red[1] + red[2] + red[3] + ob[0];
}

extern "C" void kernel_launch(void* const* d_in, const int* in_sizes, int n_in,
                              void* d_out, int out_size, void* d_ws, size_t ws_size,
                              hipStream_t stream) {
  (void)in_sizes; (void)n_in; (void)out_size; (void)ws_size;
  const float* x      = (const float*)d_in[0];
  const int*   eidx   = (const int*)d_in[1];
  const int*   src    = eidx;
  const int*   dst    = eidx + N_EDGES;
  const int*   target = (const int*)d_in[3];
  const float* W1 = (const float*)d_in[4];  const float* b1 = (const float*)d_in[5];
  const float* bn1 = (const float*)d_in[6]; const float* Wp1 = (const float*)d_in[7];
  const float* bp1 = (const float*)d_in[8];
  const float* W2 = (const float*)d_in[9];  const float* b2 = (const float*)d_in[10];
  const float* bn2 = (const float*)d_in[11]; const float* Wp2 = (const float*)d_in[12];
  const float* bp2 = (const float*)d_in[13];
  const float* W3 = (const float*)d_in[14]; const float* b3 = (const float*)d_in[15];
  const float* bn3 = (const float*)d_in[16]; const float* Wp3 = (const float*)d_in[17];
  const float* bp3 = (const float*)d_in[18];
  const float* fcg1_W = (const float*)d_in[19]; const float* fcg1_b = (const float*)d_in[20];
  const float* bn4 = (const float*)d_in[21];
  const float* emb = (const float*)d_in[22];
  const float* c1W = (const float*)d_in[23]; const float* c1b = (const float*)d_in[24];
  const float* bnx1 = (const float*)d_in[25];
  const float* c2W = (const float*)d_in[26]; const float* c2b = (const float*)d_in[27];
  const float* bnx2 = (const float*)d_in[28];
  const float* c3W = (const float*)d_in[29]; const float* c3b = (const float*)d_in[30];
  const float* bnx3 = (const float*)d_in[31];
  const float* fxt_W = (const float*)d_in[32]; const float* fxt_b = (const float*)d_in[33];
  const float* bn6 = (const float*)d_in[34];
  const float* fc1W = (const float*)d_in[35]; const float* fc1b = (const float*)d_in[36];
  const float* bn7 = (const float*)d_in[37];
  const float* fc2W = (const float*)d_in[38]; const float* fc2b = (const float*)d_in[39];
  const float* bn8 = (const float*)d_in[40];
  const float* outW = (const float*)d_in[41]; const float* outb = (const float*)d_in[42];

  char* ws = (char*)d_ws;
  size_t off = 0;
  auto alloc = [&](size_t bytes) -> void* {
    void* p = ws + off;
    off += (bytes + 255) & ~(size_t)255;
    return p;
  };
  float* dis   = (float*)alloc((size_t)N_NODES * 4);
  int*   cnt   = (int*)alloc((size_t)N_NODES * 4);
  int*   cursor= (int*)alloc((size_t)N_NODES * 4);
  int*   offs  = (int*)alloc((size_t)N_NODES * 4);
  int*   bsum  = (int*)alloc(1024);
  int*   csr   = (int*)alloc((size_t)N_EDGES * 4);
  float* cf    = (float*)alloc((size_t)N_EDGES * 4);
  float* h_a   = (float*)alloc((size_t)N_NODES * NF * 4);   // region; holds bf16 h rows (39 uints)
  float* h_b   = (float*)alloc((size_t)N_NODES * NF * 4);
  float* tbuf  = (float*)alloc((size_t)N_NODES * NF * 4);   // region; holds fp8 t (128B rows = 16.8MB)
  float* gate  = (float*)alloc((size_t)N_NODES * 4);
  float* spre  = (float*)alloc((size_t)N_NODES * 4);
  float* xsum  = (float*)alloc(512 * 156 * 4);
  float* gbuf  = (float*)alloc(512 * 128 * 4);
  float* xt    = (float*)alloc(512 * 128 * 4);
  float* xc1   = (float*)alloc(512 * 1024 * 4);
  float* xc2   = (float*)alloc(512 * 512 * 4);
  unsigned char*  t8  = (unsigned char*)tbuf;
  unsigned*       tu  = (unsigned*)tbuf;
  unsigned* ha_u = (unsigned*)h_a;  unsigned short* ha_s = (unsigned short*)h_a;
  unsigned* hb_u = (unsigned*)h_b;  unsigned short* hb_s = (unsigned short*)h_b;
  // protein-branch aliases (GNN big buffers are dead by then)
  float* O1 = h_a;                      // 512*128*128 = 33.5 MB <= 40.9 MB
  float* O2 = h_b;                      // 512*64*128  = 16.8 MB (written by conv2, after Gbuf dead)
  float* Gbuf = h_b;                    // 512*26*384  = 20.4 MB (conv1g->conv1e, dead before conv2)
  float* Wt = tbuf;                     // 1000*384    = 1.54 MB
  float* Wt2 = tbuf + 393216;           // 24576 floats (conv2 weights, i-major) + slack
  float* Wt3 = tbuf + 425984;           // 6144 floats (conv3 weights, i-major)
  float* P  = tbuf + 5242880;           // +20 MB: past fp8 t region; 512*32*128 = 8.4 MB (fits 40.9)
  float* fxt_part = h_a;                // 8*512*128 = 2 MB (O1 dead after conv2)

  hipMemsetAsync(cnt, 0, (size_t)N_NODES * 4, stream);
  hipMemsetAsync(cursor, 0, (size_t)N_NODES * 4, stream);

  k_count<<<N_EDGES / 256, 256, 0, stream>>>(dst, cnt);
  k_dis<<<N_NODES / 256, 256, 0, stream>>>(cnt, dis);
  k_scan1<<<N_NODES / 512, 512, 0, stream>>>(cnt, offs, bsum);
  k_scan2<<<1, 256, 0, stream>>>(bsum);
  k_scan3<<<N_NODES / 512, 512, 0, stream>>>(offs, bsum);
  k_fill<<<N_EDGES / 256, 256, 0, stream>>>(src, dst, offs, cursor, dis, csr, cf);

  // layer 1
  k_gemm_f32<<<N_NODES / 64, 256, 0, stream>>>(x, W1, t8);
  k_agg<<<N_NODES / 4, 256, 0, stream>>>(tu, offs, cnt, csr, cf, dis, b1, bn1, Wp1, ha_u, spre);
  k_gate<<<N_NODES / 256, 256, 0, stream>>>(spre, offs, cnt, csr, cf, dis, bp1, gate);
  k_readout<<<NB, 128, 0, stream>>>(ha_s, gate, xsum, 0);
  // layer 2
  k_gemm_bf16<<<N_NODES / 64, 256, 0, stream>>>(ha_s, gate, W2, t8);
  k_agg<<<N_NODES / 4, 256, 0, stream>>>(tu, offs, cnt, csr, cf, dis, b2, bn2, Wp2, hb_u, spre);
  k_gate<<<N_NODES / 256, 256, 0, stream>>>(spre, offs, cnt, csr, cf, dis, bp2, gate);
  k_readout<<<NB, 128, 0, stream>>>(hb_s, gate, xsum, 1);
  // layer 3
  k_gemm_bf16<<<N_NODES / 64, 256, 0, stream>>>(hb_s, gate, W3, t8);
  k_agg<<<N_NODES / 4, 256, 0, stream>>>(tu, offs, cnt, csr, cf, dis, b3, bn3, Wp3, ha_u, spre);
  k_gate<<<N_NODES / 256, 256, 0, stream>>>(spre, offs, cnt, csr, cf, dis, bp3, gate);
  k_readout<<<NB, 128, 0, stream>>>(ha_s, gate, xsum, 1);

  k_fcg<<<NB, 128, 0, stream>>>(xsum, fcg1_W, fcg1_b, bn4, gbuf);

  // protein branch (reuses h_a/h_b/tbuf regions — all GNN reads complete above)
  k_transpose_w<<<1500, 256, 0, stream>>>(c1W, Wt);
  k_transpose_w2<<<96, 256, 0, stream>>>(c2W, Wt2);
  k_transpose_w3<<<24, 256, 0, stream>>>(c3W, Wt3);
  k_conv1g<<<NB * 2, 384, 0, stream>>>(Wt, target, Gbuf);
  k_conv1e<<<NB, 512, 0, stream>>>(Gbuf, emb, c1b, bnx1, O1);
  k_conv2<<<NB * 2, 256, 0, stream>>>(O1, Wt2, c2b, bnx2, O2);
  k_conv3<<<NB, 256, 0, stream>>>(O2, Wt3, c3b, bnx3, P);
  // O1 (h_a) is dead after conv2 -> reuse for fxt partials
  k_fxt_part<<<512, 128, 0, stream>>>(P, fxt_W, fxt_part);
  k_fxt_red<<<256, 256, 0, stream>>>(fxt_part, fxt_b, bn6, xt);

  k_fc1<<<512, 256, 0, stream>>>(gbuf, xt, fc1W, fc1b, bn7, xc1);
  k_fc2<<<256, 256, 0, stream>>>(xc1, fc2W, fc2b, bn8, xc2);
  k_out<<<NB, 256, 0, stream>>>(xc2, outW, outb, (float*)d_out);
}